// Round 3
// baseline (454.016 us; speedup 1.0000x reference)
//
#include <hip/hip_runtime.h>
#include <hip/hip_bf16.h>

// Problem constants (fixed by reference setup)
#define BB 4
#define NN 4096
#define CC 96
#define N1 4097                 // x rows per batch
#define OUTROWS 1025            // 1 CLS + 1024 pooled rows per batch
#define THREADS 1024            // 16 waves/block, 1 block/CU
#define ROWS_PER_BLK 64         // edge rows per block (16384 rows / 256 blocks)
#define PATCHES_PER_BLK 16      // 64 / 4
#define NBLK 256                // 1 per CU

__device__ __forceinline__ float fast_sigmoid(float v) {
    // 1/(1+exp(-v)); overflow -> inf -> rcp -> 0 (correct limit)
    return __builtin_amdgcn_rcpf(1.0f + __expf(-v));
}

// Single fused kernel: NO workspace (d_ws poison may overlap the graph
// replay, so cross-kernel ws handoff is unsafe — round-1 lesson).
// Bit-identical math to the validated round-2 kernel:
//  - phase 1: same per-m scalar chain (c4-major, xyzw)
//  - phase 2: register a_r == old wave r; element order it*1024+lane*4+256r;
//    same shfl_down(32..1) tree; final sum ((a0+a1)+a2)+a3
//  - phase 3: same strict-> argmax chain (jax.lax.top_k tie-break)
__global__ __launch_bounds__(THREADS) void fused_pool_kernel(
    const float* __restrict__ x, const float* __restrict__ edge,
    const float* __restrict__ theta, float* __restrict__ out)
{
    __shared__ float t_lds[NN];            // 16 KB: t[b,m] for this batch
    __shared__ float s_lds[ROWS_PER_BLK];  // scores for this block's rows

    const int tid     = threadIdx.x;
    const int b       = blockIdx.x >> 6;   // / 64 blocks-per-batch
    const int blkInB  = blockIdx.x & 63;
    const int rowbase = blkInB * ROWS_PER_BLK;

    const float* xb = x + (size_t)b * N1 * CC;

    // CLS row: out[b,0,:] = x[b,0,:]
    if (blkInB == 0 && tid < CC)
        out[(size_t)b * OUTROWS * CC + tid] = xb[tid];

    // ---- Phase 1: t[m] = sum_c sigmoid(x[b,m+1,c]) * theta[c] ----
    #pragma unroll
    for (int k = 0; k < NN / THREADS; ++k) {   // 4 rows per thread
        int m = k * THREADS + tid;
        const float* xr = xb + (size_t)(m + 1) * CC;
        float acc = 0.0f;
        #pragma unroll
        for (int c4 = 0; c4 < CC / 4; ++c4) {
            float4 xv = *reinterpret_cast<const float4*>(xr + c4 * 4);
            float4 tw = *reinterpret_cast<const float4*>(theta + c4 * 4);
            acc += fast_sigmoid(xv.x) * tw.x;
            acc += fast_sigmoid(xv.y) * tw.y;
            acc += fast_sigmoid(xv.z) * tw.z;
            acc += fast_sigmoid(xv.w) * tw.w;
        }
        t_lds[m] = acc;
    }
    __syncthreads();

    // ---- Phase 2: scores, row-per-wave, ZERO barriers ----
    const int wave = tid >> 6;
    const int lane = tid & 63;
    const float* eb = edge + ((size_t)b * NN + rowbase) * NN;

    for (int q = 0; q < 4; ++q) {              // 4 rows per wave
        const int r = wave * 4 + q;
        const float* er = eb + (size_t)r * NN;
        float a0 = 0.f, a1 = 0.f, a2 = 0.f, a3 = 0.f;
        #pragma unroll
        for (int it = 0; it < 4; ++it) {
            const int base = it * 1024 + lane * 4;
            float4 e0 = *reinterpret_cast<const float4*>(er + base);
            float4 e1 = *reinterpret_cast<const float4*>(er + base + 256);
            float4 e2 = *reinterpret_cast<const float4*>(er + base + 512);
            float4 e3 = *reinterpret_cast<const float4*>(er + base + 768);
            float4 t0 = *reinterpret_cast<const float4*>(&t_lds[base]);
            float4 t1 = *reinterpret_cast<const float4*>(&t_lds[base + 256]);
            float4 t2 = *reinterpret_cast<const float4*>(&t_lds[base + 512]);
            float4 t3 = *reinterpret_cast<const float4*>(&t_lds[base + 768]);
            a0 += t0.x * fast_sigmoid(e0.x); a0 += t0.y * fast_sigmoid(e0.y);
            a0 += t0.z * fast_sigmoid(e0.z); a0 += t0.w * fast_sigmoid(e0.w);
            a1 += t1.x * fast_sigmoid(e1.x); a1 += t1.y * fast_sigmoid(e1.y);
            a1 += t1.z * fast_sigmoid(e1.z); a1 += t1.w * fast_sigmoid(e1.w);
            a2 += t2.x * fast_sigmoid(e2.x); a2 += t2.y * fast_sigmoid(e2.y);
            a2 += t2.z * fast_sigmoid(e2.z); a2 += t2.w * fast_sigmoid(e2.w);
            a3 += t3.x * fast_sigmoid(e3.x); a3 += t3.y * fast_sigmoid(e3.y);
            a3 += t3.z * fast_sigmoid(e3.z); a3 += t3.w * fast_sigmoid(e3.w);
        }
        #pragma unroll
        for (int off = 32; off > 0; off >>= 1) {
            a0 += __shfl_down(a0, off, 64);
            a1 += __shfl_down(a1, off, 64);
            a2 += __shfl_down(a2, off, 64);
            a3 += __shfl_down(a3, off, 64);
        }
        if (lane == 0) s_lds[r] = ((a0 + a1) + a2) + a3;
    }
    __syncthreads();

    // ---- Phase 3: per-patch argmax-of-4 (strict >, first index on ties)
    // + pooled write. Reference quirk: top_k idx is patch-local and
    // indexes nodes[b, 0..3, :]. One patch per wave (16 waves, 16 patches).
    {
        const int pp = wave;
        float s0 = s_lds[pp * 4 + 0], s1 = s_lds[pp * 4 + 1];
        float s2 = s_lds[pp * 4 + 2], s3 = s_lds[pp * 4 + 3];
        float best = s0; int bi = 0;
        if (s1 > best) { best = s1; bi = 1; }
        if (s2 > best) { best = s2; bi = 2; }
        if (s3 > best) { best = s3; bi = 3; }
        const float* g = xb + (size_t)(bi + 1) * CC;
        float scale = best + 1.0f;
        float* orow = out + ((size_t)b * OUTROWS + 1 +
                             blkInB * PATCHES_PER_BLK + pp) * CC;
        orow[lane] = scale * g[lane];
        if (lane < CC - 64) orow[lane + 64] = scale * g[lane + 64];
    }
}

extern "C" void kernel_launch(void* const* d_in, const int* in_sizes, int n_in,
                              void* d_out, int out_size, void* d_ws, size_t ws_size,
                              hipStream_t stream) {
    const float* x     = (const float*)d_in[0];   // (4, 4097, 96)
    const float* edge  = (const float*)d_in[1];   // (4, 4096, 4096)
    const float* theta = (const float*)d_in[2];   // (1, 96)
    float* out = (float*)d_out;                   // (4, 1025, 96)

    // Single self-contained kernel; d_ws intentionally unused.
    fused_pool_kernel<<<NBLK, THREADS, 0, stream>>>(x, edge, theta, out);
}